// Round 10
// baseline (198.877 us; speedup 1.0000x reference)
//
#include <hip/hip_runtime.h>

#define N_NODES 100000
#define NFEAT 128
#define E_EDGES 1600000
#define LRELU_SLOPE 0.2f
#define BM 32                                      // nodes per MFMA tile / bucket
#define NB2 3125                                   // 32-row buckets (= fused blocks)
#define SCAP 2048                                  // bucket capacity (16KB window)
#define HB_BLOCKS 256                              // edge chunks (hist + scatter)
#define HB_PER 6250                                // 256*6250 = E exactly
#define XB_BLOCKS 3125                             // x2bf: 16 elems/thread
#define PK_BLOCKS 320

typedef short bf16x8 __attribute__((ext_vector_type(8)));
typedef float f32x4 __attribute__((ext_vector_type(4)));
typedef uint  u32x4 __attribute__((ext_vector_type(4)));

__device__ __forceinline__ ushort f2bf(float f) {
    union { float f; uint u; } v; v.f = f;
    uint u = v.u;
    return (ushort)((u + 0x7fffu + ((u >> 16) & 1u)) >> 16);   // RNE
}
__device__ __forceinline__ float bf2f(ushort s) {
    union { uint u; float f; } v; v.u = ((uint)s) << 16;
    return v.f;
}
__device__ __forceinline__ float blo(uint u) {
    union { uint u; float f; } v; v.u = u << 16; return v.f;
}
__device__ __forceinline__ float bhi(uint u) {
    union { uint u; float f; } v; v.u = u & 0xFFFF0000u; return v.f;
}

// ---------------------------------------------------------------------------
// Mega prep kernel (independent phases, one launch):
//   blocks [0, 256)        : per-chunk LDS histogram over 3125 buckets
//   blocks [256, 3381)     : x2bf (f32 -> bf16 feature table)
//   blocks [3381, 3701)    : pack_weights (bf16 MFMA B-fragment order)
// All streaming (read-once / write-once) traffic is NONTEMPORAL: the whole
// pipeline is L2-miss-throughput bound (~3.0 TB/s invariant across R0-R9),
// so L2 capacity must be reserved for data with reuse (xb gather rows).
// ---------------------------------------------------------------------------
__global__ __launch_bounds__(256) void mega_prep(
    const int* __restrict__ er, int* __restrict__ ghist,
    const float* __restrict__ x, ushort* __restrict__ xb,
    const float* __restrict__ Wg1, const float* __restrict__ Wg2,
    const float* __restrict__ Wb1, const float* __restrict__ Wb2,
    const float* __restrict__ gcw,
    ushort* __restrict__ W1p, ushort* __restrict__ W2p)
{
    __shared__ int hist[NB2];                      // 12.5KB (hist branch only)
    const int bid = blockIdx.x;
    const int tid = threadIdx.x;

    if (bid < HB_BLOCKS) {
        for (int k = tid; k < NB2; k += 256) hist[k] = 0;
        __syncthreads();
        const int e0 = bid * HB_PER;
#pragma unroll 4
        for (int k = tid; k < HB_PER; k += 256)
            atomicAdd(&hist[__builtin_nontemporal_load(er + e0 + k) >> 5], 1);
        __syncthreads();
        for (int k = tid; k < NB2; k += 256) ghist[bid * NB2 + k] = hist[k];
    } else if (bid < HB_BLOCKS + XB_BLOCKS) {
        // ---- x -> bf16 (16 elements / thread), fully nontemporal stream ----
        size_t base = ((size_t)(bid - HB_BLOCKS) * 256 + tid) * 16;
        f32x4 a = __builtin_nontemporal_load((const f32x4*)(x + base));
        f32x4 b = __builtin_nontemporal_load((const f32x4*)(x + base + 4));
        f32x4 c = __builtin_nontemporal_load((const f32x4*)(x + base + 8));
        f32x4 d = __builtin_nontemporal_load((const f32x4*)(x + base + 12));
        u32x4 o1, o2;
        o1.x = (uint)f2bf(a.x) | ((uint)f2bf(a.y) << 16);
        o1.y = (uint)f2bf(a.z) | ((uint)f2bf(a.w) << 16);
        o1.z = (uint)f2bf(b.x) | ((uint)f2bf(b.y) << 16);
        o1.w = (uint)f2bf(b.z) | ((uint)f2bf(b.w) << 16);
        o2.x = (uint)f2bf(c.x) | ((uint)f2bf(c.y) << 16);
        o2.y = (uint)f2bf(c.z) | ((uint)f2bf(c.w) << 16);
        o2.z = (uint)f2bf(d.x) | ((uint)f2bf(d.y) << 16);
        o2.w = (uint)f2bf(d.z) | ((uint)f2bf(d.w) << 16);
        __builtin_nontemporal_store(o1, (u32x4*)(xb + base));
        __builtin_nontemporal_store(o2, (u32x4*)(xb + base + 8));
    } else {
        // ---- pack weights ----
        int idx = (bid - HB_BLOCKS - XB_BLOCKS) * 256 + tid;   // 0 .. 81919
        if (idx < 65536) {
            int jj = idx & 7;
            int lane = (idx >> 3) & 63;
            int tile = idx >> 9;          // 0..127
            int nt = tile & 15, kt = tile >> 4;
            int k = kt * 32 + (lane >> 4) * 8 + jj;
            int j = nt * 16 + (lane & 15);
            float v;
            if (j < 128) v = (k < 128) ? Wg1[j * 128 + k] : Wg2[j * 128 + (k - 128)];
            else { int c = j - 128; v = (k < 128) ? Wb1[c * 128 + k] : Wb2[c * 128 + (k - 128)]; }
            W1p[idx] = f2bf(v);
        } else if (idx < 81920) {
            int i2 = idx - 65536;
            int jj = i2 & 7;
            int lane = (i2 >> 3) & 63;
            int tile = i2 >> 9;           // 0..31
            int nt = tile & 7, kt = tile >> 3;
            int k = kt * 32 + (lane >> 4) * 8 + jj;
            int j = nt * 16 + (lane & 15);
            W2p[i2] = f2bf(gcw[k * 128 + j]);
        }
    }
}

// ---------------------------------------------------------------------------
// Single-kernel scan: block = 64 bins x 4 partials. ghist is read twice
// within the kernel (intra-kernel reuse) -> keep cached (no nt here).
// ---------------------------------------------------------------------------
__global__ __launch_bounds__(256) void scan_merge(
    const int* __restrict__ ghist, int* __restrict__ gbase,
    int* __restrict__ cursorB)
{
    __shared__ int S[4][64];
    const int tid = threadIdx.x;
    const int cl = tid & 63;              // local bin
    const int p = tid >> 6;               // partial 0..3 (64 chunks each)
    const int c = blockIdx.x * 64 + cl;
    const bool ok = c < NB2;

    int acc = 0;
    if (ok) {
#pragma unroll 8
        for (int r = p * 64; r < p * 64 + 64; r++) acc += ghist[r * NB2 + c];
    }
    S[p][cl] = acc;
    __syncthreads();

    if (ok) {
        int base = c * SCAP;
        for (int q = 0; q < p; q++) base += S[q][cl];
#pragma unroll 8
        for (int r = p * 64; r < p * 64 + 64; r++) {
            gbase[r * NB2 + c] = base;
            base += ghist[r * NB2 + c];
        }
        if (p == 3) cursorB[c] = base - c * SCAP;
    }
}

// ---------------------------------------------------------------------------
// Replay scatter: LDS slot claim, direct store to final bucket slot.
// er/ec/ev are read-once, stg is write-once-read-much-later: all NONTEMPORAL
// so the scatter doesn't flush L2 ahead of the gather-heavy fused kernel.
// staging entry: {(col<<13) | rowlocal(5b), val_bits}
// ---------------------------------------------------------------------------
__global__ __launch_bounds__(512) void scatter_edges(
    const int* __restrict__ er, const int* __restrict__ ec,
    const float* __restrict__ ev, const int* __restrict__ gbase,
    int2* __restrict__ stg)
{
    __shared__ int cur[NB2];                       // 12.5KB
    const int bid = blockIdx.x;
    const int tid = threadIdx.x;
    for (int k = tid; k < NB2; k += 512) cur[k] = gbase[bid * NB2 + k];
    __syncthreads();
    const int e0 = bid * HB_PER;
#pragma unroll 4
    for (int k = tid; k < HB_PER; k += 512) {
        int e = e0 + k;
        int r = __builtin_nontemporal_load(er + e);
        int c = __builtin_nontemporal_load(ec + e);
        float v = __builtin_nontemporal_load(ev + e);
        int t = atomicAdd(&cur[r >> 5], 1);        // LDS slot claim
        long long pk = ((long long)__float_as_int(v) << 32)
                     | (uint)((c << 13) | (r & 31));
        __builtin_nontemporal_store(pk, (long long*)(stg + t));
    }
}

// ---------------------------------------------------------------------------
// Fully fused, 8 waves/block (512 thr), EXACTLY 32KB LDS.
//   LDS map:
//     [0,     16384) asb : As[32][512B row: x(256)|nb(256)], swizzled
//     [16384, 24576) elist: 1024 int2 (sort output)
//     [24576, 25092) sort scratch (dead after gather)
//     [16384, 32768) gbb : GB[32][512B] bf16 — written only AFTER gather
//   Cache policy: the kernel is L2-miss-throughput bound (3.0 TB/s invariant,
//   R0-R9). The ONLY reused global data is xb gather rows (deg~16 re-reads)
//   -> bucket loads (read-once) and hk/mout stores (write-once) are
//   NONTEMPORAL so xb keeps the L2.
//   gather  : work-stealing rows; 4x16-lane groups; edges from LDS; unroll 2.
//   phase 1 : [G|B](32x256) = As @ W1p -> GB (LDS, bf16)
//   phase1.5: gamma/beta/m/t elementwise
//   phase 2 : h_k = (t @ W2p) / (norm+1)
// NOTE: stg aliases hk (bucket b == hk rows of block b); reads complete into
// registers before any hk store, separated by __syncthreads -> no race.
// ---------------------------------------------------------------------------
__global__ __launch_bounds__(512, 8) void fused_all(
    const int* __restrict__ cursorB, const int2* stg,
    const ushort* __restrict__ xb,
    const float* __restrict__ norm, const float* __restrict__ rvec,
    const ushort* __restrict__ W1p, const ushort* __restrict__ W2p,
    float* hk, float* __restrict__ mout)
{
    __shared__ ushort SM[16384];          // 32768 B — the ONLY LDS object
    char* smb = (char*)SM;
    char* asb = smb;                      // [0, 16384)
    int2* elist = (int2*)(smb + 16384);   // [16384, 24576): 1024 entries
    int*  h32   = (int*)(smb + 24576);
    int*  rs32  = (int*)(smb + 24704);
    int*  pd32  = (int*)(smb + 24832);
    int*  cur32 = (int*)(smb + 24960);
    int*  rowctr= (int*)(smb + 25088);
    char* gbb = smb + 16384;              // GB region (post-gather only)

    const int tid = threadIdx.x;
    const int lane = tid & 63;
    const int w = tid >> 6;               // wave 0..7
    const int g = lane >> 4;              // edge slot 0..3
    const int s = lane & 15;              // 16B chunk within row
    const int b = blockIdx.x;
    const int node0 = b * BM;             // 3125 * 32 = 100000 exact

    // ---- bucket loads (conditional, nontemporal, issued before x-stage) ----
    const int cntE = cursorB[b];
    const int2* sb = stg + (size_t)b * SCAP;
    long long raw0 = 0, raw1 = 0;
    const bool v0 = tid < cntE, v1 = tid + 512 < cntE;   // cnt ~512, max ~650
    if (v0) raw0 = __builtin_nontemporal_load((const long long*)(sb + tid));
    if (v1) raw1 = __builtin_nontemporal_load((const long long*)(sb + tid + 512));
    int2 E0, E1;
    E0.x = (int)raw0; E0.y = (int)(raw0 >> 32);
    E1.x = (int)raw1; E1.y = (int)(raw1 >> 32);

    // ---- stage x-half of As (32 rows x 16 chunks of 16B), swizzled ----
    {
        int rr = tid >> 4;                       // row 0..31
        int cq = tid & 15;                       // 16B chunk
        uint4 v = *reinterpret_cast<const uint4*>(xb + (size_t)(node0 + rr) * 128 + cq * 8);
        *(uint4*)(asb + ((rr * 512 + cq * 16) ^ ((rr & 7) << 4))) = v;
    }

    // ---- 32-bin counting sort (padded to x8) ----
    if (tid < 32) h32[tid] = 0;
    if (tid == 32) *rowctr = 0;
    __syncthreads();
    if (v0) atomicAdd(&h32[E0.x & 31], 1);
    if (v1) atomicAdd(&h32[E1.x & 31], 1);
    __syncthreads();
    if (tid < 64) {
        int pc = 0;
        if (tid < 32) { int h = h32[tid]; pc = (h + 7) & ~7; cur32[tid] = 0; }
        int v = pc;
        for (int off = 1; off < 32; off <<= 1) {
            int t = __shfl_up(v, off, 64);
            if (lane >= off) v += t;
        }
        if (tid < 32) { rs32[tid] = v - pc; pd32[tid] = pc; }
    }
    __syncthreads();
    if (v0) { int rl = E0.x & 31; elist[rs32[rl] + atomicAdd(&cur32[rl], 1)] = E0; }
    if (v1) { int rl = E1.x & 31; elist[rs32[rl] + atomicAdd(&cur32[rl], 1)] = E1; }
    if (tid < 32) {                        // pad tail with {col=0, val=0}
        int rs = rs32[tid];
        for (int j = h32[tid]; j < pd32[tid]; ++j) elist[rs + j] = make_int2(tid, 0);
    }
    __syncthreads();

    // ---- gather nb rows (SpMM): work-stealing rows, edges from LDS ----
    const char* xbase = (const char*)xb + s * 16;
    for (;;) {
        int rr;
        if (lane == 0) rr = atomicAdd(rowctr, 1);
        rr = __shfl(rr, 0, 64);
        if (rr >= 32) break;
        const int2* el = elist + rs32[rr];
        int pd = pd32[rr];
        float ac0 = 0.f, ac1 = 0.f, ac2 = 0.f, ac3 = 0.f;
        float ac4 = 0.f, ac5 = 0.f, ac6 = 0.f, ac7 = 0.f;
#pragma unroll 2
        for (int j = 0; j < pd; j += 8) {
            int2 e0 = el[j + g];
            int2 e1 = el[j + 4 + g];
            uint4 q0 = *reinterpret_cast<const uint4*>(xbase + (e0.x >> 5));  // >>5 = col*256
            uint4 q1 = *reinterpret_cast<const uint4*>(xbase + (e1.x >> 5));
            float f0 = __int_as_float(e0.y);
            float f1 = __int_as_float(e1.y);
            ac0 += f0 * blo(q0.x); ac1 += f0 * bhi(q0.x);
            ac2 += f0 * blo(q0.y); ac3 += f0 * bhi(q0.y);
            ac4 += f0 * blo(q0.z); ac5 += f0 * bhi(q0.z);
            ac6 += f0 * blo(q0.w); ac7 += f0 * bhi(q0.w);
            ac0 += f1 * blo(q1.x); ac1 += f1 * bhi(q1.x);
            ac2 += f1 * blo(q1.y); ac3 += f1 * bhi(q1.y);
            ac4 += f1 * blo(q1.z); ac5 += f1 * bhi(q1.z);
            ac6 += f1 * blo(q1.w); ac7 += f1 * bhi(q1.w);
        }
        ac0 += __shfl_xor(ac0, 16, 64); ac0 += __shfl_xor(ac0, 32, 64);
        ac1 += __shfl_xor(ac1, 16, 64); ac1 += __shfl_xor(ac1, 32, 64);
        ac2 += __shfl_xor(ac2, 16, 64); ac2 += __shfl_xor(ac2, 32, 64);
        ac3 += __shfl_xor(ac3, 16, 64); ac3 += __shfl_xor(ac3, 32, 64);
        ac4 += __shfl_xor(ac4, 16, 64); ac4 += __shfl_xor(ac4, 32, 64);
        ac5 += __shfl_xor(ac5, 16, 64); ac5 += __shfl_xor(ac5, 32, 64);
        ac6 += __shfl_xor(ac6, 16, 64); ac6 += __shfl_xor(ac6, 32, 64);
        ac7 += __shfl_xor(ac7, 16, 64); ac7 += __shfl_xor(ac7, 32, 64);
        if (g == 0) {
            uint4 o;
            o.x = (uint)f2bf(ac0) | ((uint)f2bf(ac1) << 16);
            o.y = (uint)f2bf(ac2) | ((uint)f2bf(ac3) << 16);
            o.z = (uint)f2bf(ac4) | ((uint)f2bf(ac5) << 16);
            o.w = (uint)f2bf(ac6) | ((uint)f2bf(ac7) << 16);
            *(uint4*)(asb + ((rr * 512 + 256 + s * 16) ^ ((rr & 7) << 4))) = o;
        }
    }
    __syncthreads();

    // ---- phase 1: [G|B] = As @ W1  (each wave: 2 N-tiles) ----
    f32x4 acc[2][2];
#pragma unroll
    for (int mt = 0; mt < 2; mt++)
#pragma unroll
        for (int nl = 0; nl < 2; nl++) acc[mt][nl] = (f32x4){0.f, 0.f, 0.f, 0.f};

#pragma unroll
    for (int kt = 0; kt < 8; kt++) {
        bf16x8 af[2];
#pragma unroll
        for (int mt = 0; mt < 2; mt++) {
            int row = mt * 16 + (lane & 15);
            int off = (row * 512 + kt * 64 + (lane >> 4) * 16) ^ ((row & 7) << 4);
            af[mt] = *(bf16x8*)(asb + off);
        }
#pragma unroll
        for (int nl = 0; nl < 2; nl++) {
            int nt = w * 2 + nl;
            bf16x8 bfg = *(const bf16x8*)(W1p + (((kt * 16 + nt) * 64 + lane) << 3));
#pragma unroll
            for (int mt = 0; mt < 2; mt++)
                acc[mt][nl] = __builtin_amdgcn_mfma_f32_16x16x32_bf16(af[mt], bfg, acc[mt][nl], 0, 0, 0);
        }
    }

    // ---- write GB to LDS as bf16 (elist/scratch dead past this barrier) ----
#pragma unroll
    for (int mt = 0; mt < 2; mt++)
#pragma unroll
        for (int nl = 0; nl < 2; nl++) {
            int j = (w * 2 + nl) * 16 + (lane & 15);
#pragma unroll
            for (int reg = 0; reg < 4; reg++) {
                int row = mt * 16 + (lane >> 4) * 4 + reg;
                int off = (row * 512 + j * 2) ^ ((row & 7) << 4);
                *(ushort*)(gbb + off) = f2bf(acc[mt][nl][reg]);
            }
        }
    __syncthreads();

    // ---- phase 1.5: elementwise; write m (nontemporal); t -> As in place ----
    {
        int c = tid & 127;
        float rv = rvec[c];
        int rg = tid >> 7;                // 0..3
#pragma unroll 4
        for (int i = 0; i < 8; i++) {
            int row = rg * 8 + i;
            int swz = (row & 7) << 4;
            int bx = (row * 512 + c * 2) ^ swz;
            int bn = (row * 512 + 256 + c * 2) ^ swz;
            float graw = bf2f(*(ushort*)(gbb + bx));
            float braw = bf2f(*(ushort*)(gbb + bn));
            float xv = bf2f(*(ushort*)(asb + bx));
            float nv = bf2f(*(ushort*)(asb + bn));
            float gamma = ((graw > 0.f) ? graw : LRELU_SLOPE * graw) + 1.f;
            float beta = (braw > 0.f) ? braw : LRELU_SLOPE * braw;
            float gb_ = gamma * rv + beta;
            float mv = xv + gb_ - nv;
            float tv = 2.f * xv + gb_;
            __builtin_nontemporal_store(mv, &mout[(size_t)(node0 + row) * 128 + c]);
            *(ushort*)(asb + bx) = f2bf(tv);
        }
    }
    __syncthreads();

    // ---- phase 2: h_k = t @ W2 / (norm+1)  (each wave: 1 N-tile) ----
    f32x4 acc2[2];
#pragma unroll
    for (int mt = 0; mt < 2; mt++) acc2[mt] = (f32x4){0.f, 0.f, 0.f, 0.f};

#pragma unroll
    for (int kt = 0; kt < 4; kt++) {
        bf16x8 af[2];
#pragma unroll
        for (int mt = 0; mt < 2; mt++) {
            int row = mt * 16 + (lane & 15);
            int off = (row * 512 + kt * 64 + (lane >> 4) * 16) ^ ((row & 7) << 4);
            af[mt] = *(bf16x8*)(asb + off);
        }
        bf16x8 bfg = *(const bf16x8*)(W2p + (((kt * 8 + w) * 64 + lane) << 3));
#pragma unroll
        for (int mt = 0; mt < 2; mt++)
            acc2[mt] = __builtin_amdgcn_mfma_f32_16x16x32_bf16(af[mt], bfg, acc2[mt], 0, 0, 0);
    }

#pragma unroll
    for (int mt = 0; mt < 2; mt++) {
        int col = w * 16 + (lane & 15);
#pragma unroll
        for (int reg = 0; reg < 4; reg++) {
            int row = mt * 16 + (lane >> 4) * 4 + reg;
            int node = node0 + row;
            float inv = 1.f / (norm[node] + 1.f);
            __builtin_nontemporal_store(acc2[mt][reg] * inv,
                                        &hk[(size_t)node * 128 + col]);
        }
    }
}

extern "C" void kernel_launch(void* const* d_in, const int* in_sizes, int n_in,
                              void* d_out, int out_size, void* d_ws, size_t ws_size,
                              hipStream_t stream)
{
    const float* x    = (const float*)d_in[0];
    const int*   er   = (const int*)d_in[1];
    const int*   ec   = (const int*)d_in[2];
    const float* ev   = (const float*)d_in[3];
    const float* norm = (const float*)d_in[4];
    const float* Wg1  = (const float*)d_in[5];
    const float* Wg2  = (const float*)d_in[6];
    const float* Wb1  = (const float*)d_in[7];
    const float* Wb2  = (const float*)d_in[8];
    const float* r    = (const float*)d_in[9];
    const float* gcw  = (const float*)d_in[10];

    float* out  = (float*)d_out;
    float* hk   = out;
    float* mout = out + (size_t)N_NODES * NFEAT;

    // workspace layout (~32MB total)
    ushort* xb      = (ushort*)d_ws;                         // N*128 bf16 = 25.6MB
    ushort* W1p     = xb + (size_t)N_NODES * NFEAT;          // 65536
    ushort* W2p     = W1p + 65536;                           // 16384
    int*    cursorB = (int*)(W2p + 16384);                   // NB2
    int*    ghist   = cursorB + NB2;                         // 256*3125 = 3.2MB
    int*    gbase   = ghist + HB_BLOCKS * NB2;               // 3.2MB

    // bucket staging aliases hk: bucket b == hk rows of fused block b
    int2* stg = (int2*)hk;                                   // NB2*SCAP*8 = 51.2MB

    mega_prep<<<HB_BLOCKS + XB_BLOCKS + PK_BLOCKS, 256, 0, stream>>>(
        er, ghist, x, xb, Wg1, Wg2, Wb1, Wb2, gcw, W1p, W2p);

    scan_merge<<<(NB2 + 63) / 64, 256, 0, stream>>>(ghist, gbase, cursorB);

    scatter_edges<<<HB_BLOCKS, 512, 0, stream>>>(er, ec, ev, gbase, stg);

    fused_all<<<NB2, 512, 0, stream>>>(
        cursorB, stg, xb, norm, r, W1p, W2p, hk, mout);
}

// Round 11
// 169.561 us; speedup vs baseline: 1.1729x; 1.1729x over previous
//
#include <hip/hip_runtime.h>

#define N_NODES 100000
#define NFEAT 128
#define E_EDGES 1600000
#define LRELU_SLOPE 0.2f
#define BM 32                                      // nodes per MFMA tile / bucket
#define NB2 3125                                   // 32-row buckets (= fused blocks)
#define SCAP 2048                                  // bucket capacity (16KB window)
#define HB_BLOCKS 256                              // edge chunks (hist + scatter)
#define HB_PER 6250                                // 256*6250 = E exactly
#define XB_BLOCKS 3125                             // x2bf: 16 elems/thread
#define PK_BLOCKS 320

typedef short bf16x8 __attribute__((ext_vector_type(8)));
typedef float f32x4 __attribute__((ext_vector_type(4)));
typedef uint  u32x4 __attribute__((ext_vector_type(4)));

__device__ __forceinline__ ushort f2bf(float f) {
    union { float f; uint u; } v; v.f = f;
    uint u = v.u;
    return (ushort)((u + 0x7fffu + ((u >> 16) & 1u)) >> 16);   // RNE
}
__device__ __forceinline__ float bf2f(ushort s) {
    union { uint u; float f; } v; v.u = ((uint)s) << 16;
    return v.f;
}
__device__ __forceinline__ float blo(uint u) {
    union { uint u; float f; } v; v.u = u << 16; return v.f;
}
__device__ __forceinline__ float bhi(uint u) {
    union { uint u; float f; } v; v.u = u & 0xFFFF0000u; return v.f;
}

// ---------------------------------------------------------------------------
// Mega prep kernel (independent phases, one launch):
//   blocks [0, 256)        : per-chunk LDS histogram over 3125 buckets
//   blocks [256, 3381)     : x2bf (f32 -> bf16 feature table)
//   blocks [3381, 3701)    : pack_weights (bf16 MFMA B-fragment order)
// nt policy (R10 lesson): nontemporal ONLY on coalesced full-line streams.
// Scattered stores must stay cached (L2 write-coalescing) — see scatter.
// ---------------------------------------------------------------------------
__global__ __launch_bounds__(256) void mega_prep(
    const int* __restrict__ er, int* __restrict__ ghist,
    const float* __restrict__ x, ushort* __restrict__ xb,
    const float* __restrict__ Wg1, const float* __restrict__ Wg2,
    const float* __restrict__ Wb1, const float* __restrict__ Wb2,
    const float* __restrict__ gcw,
    ushort* __restrict__ W1p, ushort* __restrict__ W2p)
{
    __shared__ int hist[NB2];                      // 12.5KB (hist branch only)
    const int bid = blockIdx.x;
    const int tid = threadIdx.x;

    if (bid < HB_BLOCKS) {
        for (int k = tid; k < NB2; k += 256) hist[k] = 0;
        __syncthreads();
        const int e0 = bid * HB_PER;
#pragma unroll 4
        for (int k = tid; k < HB_PER; k += 256)
            atomicAdd(&hist[__builtin_nontemporal_load(er + e0 + k) >> 5], 1);
        __syncthreads();
        for (int k = tid; k < NB2; k += 256) ghist[bid * NB2 + k] = hist[k];
    } else if (bid < HB_BLOCKS + XB_BLOCKS) {
        // ---- x -> bf16 (16 elements / thread), fully nontemporal stream ----
        size_t base = ((size_t)(bid - HB_BLOCKS) * 256 + tid) * 16;
        f32x4 a = __builtin_nontemporal_load((const f32x4*)(x + base));
        f32x4 b = __builtin_nontemporal_load((const f32x4*)(x + base + 4));
        f32x4 c = __builtin_nontemporal_load((const f32x4*)(x + base + 8));
        f32x4 d = __builtin_nontemporal_load((const f32x4*)(x + base + 12));
        u32x4 o1, o2;
        o1.x = (uint)f2bf(a.x) | ((uint)f2bf(a.y) << 16);
        o1.y = (uint)f2bf(a.z) | ((uint)f2bf(a.w) << 16);
        o1.z = (uint)f2bf(b.x) | ((uint)f2bf(b.y) << 16);
        o1.w = (uint)f2bf(b.z) | ((uint)f2bf(b.w) << 16);
        o2.x = (uint)f2bf(c.x) | ((uint)f2bf(c.y) << 16);
        o2.y = (uint)f2bf(c.z) | ((uint)f2bf(c.w) << 16);
        o2.z = (uint)f2bf(d.x) | ((uint)f2bf(d.y) << 16);
        o2.w = (uint)f2bf(d.z) | ((uint)f2bf(d.w) << 16);
        __builtin_nontemporal_store(o1, (u32x4*)(xb + base));
        __builtin_nontemporal_store(o2, (u32x4*)(xb + base + 8));
    } else {
        // ---- pack weights ----
        int idx = (bid - HB_BLOCKS - XB_BLOCKS) * 256 + tid;   // 0 .. 81919
        if (idx < 65536) {
            int jj = idx & 7;
            int lane = (idx >> 3) & 63;
            int tile = idx >> 9;          // 0..127
            int nt = tile & 15, kt = tile >> 4;
            int k = kt * 32 + (lane >> 4) * 8 + jj;
            int j = nt * 16 + (lane & 15);
            float v;
            if (j < 128) v = (k < 128) ? Wg1[j * 128 + k] : Wg2[j * 128 + (k - 128)];
            else { int c = j - 128; v = (k < 128) ? Wb1[c * 128 + k] : Wb2[c * 128 + (k - 128)]; }
            W1p[idx] = f2bf(v);
        } else if (idx < 81920) {
            int i2 = idx - 65536;
            int jj = i2 & 7;
            int lane = (i2 >> 3) & 63;
            int tile = i2 >> 9;           // 0..31
            int nt = tile & 7, kt = tile >> 3;
            int k = kt * 32 + (lane >> 4) * 8 + jj;
            int j = nt * 16 + (lane & 15);
            W2p[i2] = f2bf(gcw[k * 128 + j]);
        }
    }
}

// ---------------------------------------------------------------------------
// Single-kernel scan: block = 64 bins x 4 partials. ghist read twice within
// the kernel (intra-kernel reuse) -> cached.
// ---------------------------------------------------------------------------
__global__ __launch_bounds__(256) void scan_merge(
    const int* __restrict__ ghist, int* __restrict__ gbase,
    int* __restrict__ cursorB)
{
    __shared__ int S[4][64];
    const int tid = threadIdx.x;
    const int cl = tid & 63;              // local bin
    const int p = tid >> 6;               // partial 0..3 (64 chunks each)
    const int c = blockIdx.x * 64 + cl;
    const bool ok = c < NB2;

    int acc = 0;
    if (ok) {
#pragma unroll 8
        for (int r = p * 64; r < p * 64 + 64; r++) acc += ghist[r * NB2 + c];
    }
    S[p][cl] = acc;
    __syncthreads();

    if (ok) {
        int base = c * SCAP;
        for (int q = 0; q < p; q++) base += S[q][cl];
#pragma unroll 8
        for (int r = p * 64; r < p * 64 + 64; r++) {
            gbase[r * NB2 + c] = base;
            base += ghist[r * NB2 + c];
        }
        if (p == 3) cursorB[c] = base - c * SCAP;
    }
}

// ---------------------------------------------------------------------------
// Replay scatter: LDS slot claim, direct store to final bucket slot.
// Loads (coalesced read-once) are nontemporal; the SCATTERED stg store is
// CACHED — R10 measured nt here at ~+50us (8B write-no-allocate = partial-line
// HBM RMW per edge; L2 write-coalescing is essential for scattered stores).
// staging entry: {(col<<13) | rowlocal(5b), val_bits}
// ---------------------------------------------------------------------------
__global__ __launch_bounds__(512) void scatter_edges(
    const int* __restrict__ er, const int* __restrict__ ec,
    const float* __restrict__ ev, const int* __restrict__ gbase,
    int2* __restrict__ stg)
{
    __shared__ int cur[NB2];                       // 12.5KB
    const int bid = blockIdx.x;
    const int tid = threadIdx.x;
    for (int k = tid; k < NB2; k += 512) cur[k] = gbase[bid * NB2 + k];
    __syncthreads();
    const int e0 = bid * HB_PER;
#pragma unroll 4
    for (int k = tid; k < HB_PER; k += 512) {
        int e = e0 + k;
        int r = __builtin_nontemporal_load(er + e);
        int c = __builtin_nontemporal_load(ec + e);
        float v = __builtin_nontemporal_load(ev + e);
        int t = atomicAdd(&cur[r >> 5], 1);        // LDS slot claim
        int2 o;
        o.x = (c << 13) | (r & 31);
        o.y = __float_as_int(v);
        stg[t] = o;                                // cached scattered store
    }
}

// ---------------------------------------------------------------------------
// Fully fused, 8 waves/block (512 thr), EXACTLY 32KB LDS.
//   LDS map:
//     [0,     16384) asb : As[32][512B row: x(256)|nb(256)], swizzled
//     [16384, 24576) elist: 1024 int2 (sort output)
//     [24576, 25092) sort scratch (dead after gather)
//     [16384, 32768) gbb : GB[32][512B] bf16 — written only AFTER gather
//   Cache policy: kernel is L2-miss-throughput bound (3.0 TB/s invariant).
//   Only reused global data is xb gather rows -> bucket loads (read-once)
//   and hk/mout stores (write-once, coalesced) are NONTEMPORAL (R10: −4MB
//   FETCH, −1.3us).
//   gather  : work-stealing rows; 4x16-lane groups; edges from LDS; unroll 2.
//   phase 1 : [G|B](32x256) = As @ W1p -> GB (LDS, bf16)
//   phase1.5: gamma/beta/m/t elementwise
//   phase 2 : h_k = (t @ W2p) / (norm+1)
// NOTE: stg aliases hk (bucket b == hk rows of block b); reads complete into
// registers before any hk store, separated by __syncthreads -> no race.
// ---------------------------------------------------------------------------
__global__ __launch_bounds__(512, 8) void fused_all(
    const int* __restrict__ cursorB, const int2* stg,
    const ushort* __restrict__ xb,
    const float* __restrict__ norm, const float* __restrict__ rvec,
    const ushort* __restrict__ W1p, const ushort* __restrict__ W2p,
    float* hk, float* __restrict__ mout)
{
    __shared__ ushort SM[16384];          // 32768 B — the ONLY LDS object
    char* smb = (char*)SM;
    char* asb = smb;                      // [0, 16384)
    int2* elist = (int2*)(smb + 16384);   // [16384, 24576): 1024 entries
    int*  h32   = (int*)(smb + 24576);
    int*  rs32  = (int*)(smb + 24704);
    int*  pd32  = (int*)(smb + 24832);
    int*  cur32 = (int*)(smb + 24960);
    int*  rowctr= (int*)(smb + 25088);
    char* gbb = smb + 16384;              // GB region (post-gather only)

    const int tid = threadIdx.x;
    const int lane = tid & 63;
    const int w = tid >> 6;               // wave 0..7
    const int g = lane >> 4;              // edge slot 0..3
    const int s = lane & 15;              // 16B chunk within row
    const int b = blockIdx.x;
    const int node0 = b * BM;             // 3125 * 32 = 100000 exact

    // ---- bucket loads (conditional, nontemporal, issued before x-stage) ----
    const int cntE = cursorB[b];
    const int2* sb = stg + (size_t)b * SCAP;
    long long raw0 = 0, raw1 = 0;
    const bool v0 = tid < cntE, v1 = tid + 512 < cntE;   // cnt ~512, max ~650
    if (v0) raw0 = __builtin_nontemporal_load((const long long*)(sb + tid));
    if (v1) raw1 = __builtin_nontemporal_load((const long long*)(sb + tid + 512));
    int2 E0, E1;
    E0.x = (int)raw0; E0.y = (int)(raw0 >> 32);
    E1.x = (int)raw1; E1.y = (int)(raw1 >> 32);

    // ---- stage x-half of As (32 rows x 16 chunks of 16B), swizzled ----
    {
        int rr = tid >> 4;                       // row 0..31
        int cq = tid & 15;                       // 16B chunk
        uint4 v = *reinterpret_cast<const uint4*>(xb + (size_t)(node0 + rr) * 128 + cq * 8);
        *(uint4*)(asb + ((rr * 512 + cq * 16) ^ ((rr & 7) << 4))) = v;
    }

    // ---- 32-bin counting sort (padded to x8) ----
    if (tid < 32) h32[tid] = 0;
    if (tid == 32) *rowctr = 0;
    __syncthreads();
    if (v0) atomicAdd(&h32[E0.x & 31], 1);
    if (v1) atomicAdd(&h32[E1.x & 31], 1);
    __syncthreads();
    if (tid < 64) {
        int pc = 0;
        if (tid < 32) { int h = h32[tid]; pc = (h + 7) & ~7; cur32[tid] = 0; }
        int v = pc;
        for (int off = 1; off < 32; off <<= 1) {
            int t = __shfl_up(v, off, 64);
            if (lane >= off) v += t;
        }
        if (tid < 32) { rs32[tid] = v - pc; pd32[tid] = pc; }
    }
    __syncthreads();
    if (v0) { int rl = E0.x & 31; elist[rs32[rl] + atomicAdd(&cur32[rl], 1)] = E0; }
    if (v1) { int rl = E1.x & 31; elist[rs32[rl] + atomicAdd(&cur32[rl], 1)] = E1; }
    if (tid < 32) {                        // pad tail with {col=0, val=0}
        int rs = rs32[tid];
        for (int j = h32[tid]; j < pd32[tid]; ++j) elist[rs + j] = make_int2(tid, 0);
    }
    __syncthreads();

    // ---- gather nb rows (SpMM): work-stealing rows, edges from LDS ----
    const char* xbase = (const char*)xb + s * 16;
    for (;;) {
        int rr;
        if (lane == 0) rr = atomicAdd(rowctr, 1);
        rr = __shfl(rr, 0, 64);
        if (rr >= 32) break;
        const int2* el = elist + rs32[rr];
        int pd = pd32[rr];
        float ac0 = 0.f, ac1 = 0.f, ac2 = 0.f, ac3 = 0.f;
        float ac4 = 0.f, ac5 = 0.f, ac6 = 0.f, ac7 = 0.f;
#pragma unroll 2
        for (int j = 0; j < pd; j += 8) {
            int2 e0 = el[j + g];
            int2 e1 = el[j + 4 + g];
            uint4 q0 = *reinterpret_cast<const uint4*>(xbase + (e0.x >> 5));  // >>5 = col*256
            uint4 q1 = *reinterpret_cast<const uint4*>(xbase + (e1.x >> 5));
            float f0 = __int_as_float(e0.y);
            float f1 = __int_as_float(e1.y);
            ac0 += f0 * blo(q0.x); ac1 += f0 * bhi(q0.x);
            ac2 += f0 * blo(q0.y); ac3 += f0 * bhi(q0.y);
            ac4 += f0 * blo(q0.z); ac5 += f0 * bhi(q0.z);
            ac6 += f0 * blo(q0.w); ac7 += f0 * bhi(q0.w);
            ac0 += f1 * blo(q1.x); ac1 += f1 * bhi(q1.x);
            ac2 += f1 * blo(q1.y); ac3 += f1 * bhi(q1.y);
            ac4 += f1 * blo(q1.z); ac5 += f1 * bhi(q1.z);
            ac6 += f1 * blo(q1.w); ac7 += f1 * bhi(q1.w);
        }
        ac0 += __shfl_xor(ac0, 16, 64); ac0 += __shfl_xor(ac0, 32, 64);
        ac1 += __shfl_xor(ac1, 16, 64); ac1 += __shfl_xor(ac1, 32, 64);
        ac2 += __shfl_xor(ac2, 16, 64); ac2 += __shfl_xor(ac2, 32, 64);
        ac3 += __shfl_xor(ac3, 16, 64); ac3 += __shfl_xor(ac3, 32, 64);
        ac4 += __shfl_xor(ac4, 16, 64); ac4 += __shfl_xor(ac4, 32, 64);
        ac5 += __shfl_xor(ac5, 16, 64); ac5 += __shfl_xor(ac5, 32, 64);
        ac6 += __shfl_xor(ac6, 16, 64); ac6 += __shfl_xor(ac6, 32, 64);
        ac7 += __shfl_xor(ac7, 16, 64); ac7 += __shfl_xor(ac7, 32, 64);
        if (g == 0) {
            uint4 o;
            o.x = (uint)f2bf(ac0) | ((uint)f2bf(ac1) << 16);
            o.y = (uint)f2bf(ac2) | ((uint)f2bf(ac3) << 16);
            o.z = (uint)f2bf(ac4) | ((uint)f2bf(ac5) << 16);
            o.w = (uint)f2bf(ac6) | ((uint)f2bf(ac7) << 16);
            *(uint4*)(asb + ((rr * 512 + 256 + s * 16) ^ ((rr & 7) << 4))) = o;
        }
    }
    __syncthreads();

    // ---- phase 1: [G|B] = As @ W1  (each wave: 2 N-tiles) ----
    f32x4 acc[2][2];
#pragma unroll
    for (int mt = 0; mt < 2; mt++)
#pragma unroll
        for (int nl = 0; nl < 2; nl++) acc[mt][nl] = (f32x4){0.f, 0.f, 0.f, 0.f};

#pragma unroll
    for (int kt = 0; kt < 8; kt++) {
        bf16x8 af[2];
#pragma unroll
        for (int mt = 0; mt < 2; mt++) {
            int row = mt * 16 + (lane & 15);
            int off = (row * 512 + kt * 64 + (lane >> 4) * 16) ^ ((row & 7) << 4);
            af[mt] = *(bf16x8*)(asb + off);
        }
#pragma unroll
        for (int nl = 0; nl < 2; nl++) {
            int nt = w * 2 + nl;
            bf16x8 bfg = *(const bf16x8*)(W1p + (((kt * 16 + nt) * 64 + lane) << 3));
#pragma unroll
            for (int mt = 0; mt < 2; mt++)
                acc[mt][nl] = __builtin_amdgcn_mfma_f32_16x16x32_bf16(af[mt], bfg, acc[mt][nl], 0, 0, 0);
        }
    }

    // ---- write GB to LDS as bf16 (elist/scratch dead past this barrier) ----
#pragma unroll
    for (int mt = 0; mt < 2; mt++)
#pragma unroll
        for (int nl = 0; nl < 2; nl++) {
            int j = (w * 2 + nl) * 16 + (lane & 15);
#pragma unroll
            for (int reg = 0; reg < 4; reg++) {
                int row = mt * 16 + (lane >> 4) * 4 + reg;
                int off = (row * 512 + j * 2) ^ ((row & 7) << 4);
                *(ushort*)(gbb + off) = f2bf(acc[mt][nl][reg]);
            }
        }
    __syncthreads();

    // ---- phase 1.5: elementwise; write m (nontemporal); t -> As in place ----
    {
        int c = tid & 127;
        float rv = rvec[c];
        int rg = tid >> 7;                // 0..3
#pragma unroll 4
        for (int i = 0; i < 8; i++) {
            int row = rg * 8 + i;
            int swz = (row & 7) << 4;
            int bx = (row * 512 + c * 2) ^ swz;
            int bn = (row * 512 + 256 + c * 2) ^ swz;
            float graw = bf2f(*(ushort*)(gbb + bx));
            float braw = bf2f(*(ushort*)(gbb + bn));
            float xv = bf2f(*(ushort*)(asb + bx));
            float nv = bf2f(*(ushort*)(asb + bn));
            float gamma = ((graw > 0.f) ? graw : LRELU_SLOPE * graw) + 1.f;
            float beta = (braw > 0.f) ? braw : LRELU_SLOPE * braw;
            float gb_ = gamma * rv + beta;
            float mv = xv + gb_ - nv;
            float tv = 2.f * xv + gb_;
            __builtin_nontemporal_store(mv, &mout[(size_t)(node0 + row) * 128 + c]);
            *(ushort*)(asb + bx) = f2bf(tv);
        }
    }
    __syncthreads();

    // ---- phase 2: h_k = t @ W2 / (norm+1)  (each wave: 1 N-tile) ----
    f32x4 acc2[2];
#pragma unroll
    for (int mt = 0; mt < 2; mt++) acc2[mt] = (f32x4){0.f, 0.f, 0.f, 0.f};

#pragma unroll
    for (int kt = 0; kt < 4; kt++) {
        bf16x8 af[2];
#pragma unroll
        for (int mt = 0; mt < 2; mt++) {
            int row = mt * 16 + (lane & 15);
            int off = (row * 512 + kt * 64 + (lane >> 4) * 16) ^ ((row & 7) << 4);
            af[mt] = *(bf16x8*)(asb + off);
        }
        bf16x8 bfg = *(const bf16x8*)(W2p + (((kt * 8 + w) * 64 + lane) << 3));
#pragma unroll
        for (int mt = 0; mt < 2; mt++)
            acc2[mt] = __builtin_amdgcn_mfma_f32_16x16x32_bf16(af[mt], bfg, acc2[mt], 0, 0, 0);
    }

#pragma unroll
    for (int mt = 0; mt < 2; mt++) {
        int col = w * 16 + (lane & 15);
#pragma unroll
        for (int reg = 0; reg < 4; reg++) {
            int row = mt * 16 + (lane >> 4) * 4 + reg;
            int node = node0 + row;
            float inv = 1.f / (norm[node] + 1.f);
            __builtin_nontemporal_store(acc2[mt][reg] * inv,
                                        &hk[(size_t)node * 128 + col]);
        }
    }
}

extern "C" void kernel_launch(void* const* d_in, const int* in_sizes, int n_in,
                              void* d_out, int out_size, void* d_ws, size_t ws_size,
                              hipStream_t stream)
{
    const float* x    = (const float*)d_in[0];
    const int*   er   = (const int*)d_in[1];
    const int*   ec   = (const int*)d_in[2];
    const float* ev   = (const float*)d_in[3];
    const float* norm = (const float*)d_in[4];
    const float* Wg1  = (const float*)d_in[5];
    const float* Wg2  = (const float*)d_in[6];
    const float* Wb1  = (const float*)d_in[7];
    const float* Wb2  = (const float*)d_in[8];
    const float* r    = (const float*)d_in[9];
    const float* gcw  = (const float*)d_in[10];

    float* out  = (float*)d_out;
    float* hk   = out;
    float* mout = out + (size_t)N_NODES * NFEAT;

    // workspace layout (~32MB total)
    ushort* xb      = (ushort*)d_ws;                         // N*128 bf16 = 25.6MB
    ushort* W1p     = xb + (size_t)N_NODES * NFEAT;          // 65536
    ushort* W2p     = W1p + 65536;                           // 16384
    int*    cursorB = (int*)(W2p + 16384);                   // NB2
    int*    ghist   = cursorB + NB2;                         // 256*3125 = 3.2MB
    int*    gbase   = ghist + HB_BLOCKS * NB2;               // 3.2MB

    // bucket staging aliases hk: bucket b == hk rows of fused block b
    int2* stg = (int2*)hk;                                   // NB2*SCAP*8 = 51.2MB

    mega_prep<<<HB_BLOCKS + XB_BLOCKS + PK_BLOCKS, 256, 0, stream>>>(
        er, ghist, x, xb, Wg1, Wg2, Wb1, Wb2, gcw, W1p, W2p);

    scan_merge<<<(NB2 + 63) / 64, 256, 0, stream>>>(ghist, gbase, cursorB);

    scatter_edges<<<HB_BLOCKS, 512, 0, stream>>>(er, ec, ev, gbase, stg);

    fused_all<<<NB2, 512, 0, stream>>>(
        cursorB, stg, xb, norm, r, W1p, W2p, hk, mout);
}

// Round 12
// 144.553 us; speedup vs baseline: 1.3758x; 1.1730x over previous
//
#include <hip/hip_runtime.h>

#define N_NODES 100000
#define NFEAT 128
#define E_EDGES 1600000
#define LRELU_SLOPE 0.2f
#define BM 32                                      // nodes per MFMA tile / bucket
#define NB2 3125                                   // 32-row buckets (= fused blocks)
#define SCAP 2048                                  // bucket capacity (16KB window)
#define HB_BLOCKS 256                              // edge chunks (hist + scatter)
#define HB_PER 6250                                // 256*6250 = E exactly
#define XB_BLOCKS 3125                             // x2bf: 16 elems/thread
#define PK_BLOCKS 320

typedef short bf16x8 __attribute__((ext_vector_type(8)));
typedef float f32x4 __attribute__((ext_vector_type(4)));

__device__ __forceinline__ ushort f2bf(float f) {
    union { float f; uint u; } v; v.f = f;
    uint u = v.u;
    return (ushort)((u + 0x7fffu + ((u >> 16) & 1u)) >> 16);   // RNE
}
__device__ __forceinline__ float bf2f(ushort s) {
    union { uint u; float f; } v; v.u = ((uint)s) << 16;
    return v.f;
}
__device__ __forceinline__ float blo(uint u) {
    union { uint u; float f; } v; v.u = u << 16; return v.f;
}
__device__ __forceinline__ float bhi(uint u) {
    union { uint u; float f; } v; v.u = u & 0xFFFF0000u; return v.f;
}

// ---------------------------------------------------------------------------
// Mega prep kernel (R9 form — fully cached. R10/R11 A/B: nt hints in prep
// REGRESS ~27us because er is read twice (hist+scatter), xb is re-read by
// the gather, and nt defeats L1/L2 line reuse. nt lives ONLY in fused_all.)
//   blocks [0, 256)        : per-chunk LDS histogram over 3125 buckets
//   blocks [256, 3381)     : x2bf (f32 -> bf16 feature table)
//   blocks [3381, 3701)    : pack_weights (bf16 MFMA B-fragment order)
// ---------------------------------------------------------------------------
__global__ __launch_bounds__(256) void mega_prep(
    const int* __restrict__ er, int* __restrict__ ghist,
    const float* __restrict__ x, ushort* __restrict__ xb,
    const float* __restrict__ Wg1, const float* __restrict__ Wg2,
    const float* __restrict__ Wb1, const float* __restrict__ Wb2,
    const float* __restrict__ gcw,
    ushort* __restrict__ W1p, ushort* __restrict__ W2p)
{
    __shared__ int hist[NB2];                      // 12.5KB (hist branch only)
    const int bid = blockIdx.x;
    const int tid = threadIdx.x;

    if (bid < HB_BLOCKS) {
        for (int k = tid; k < NB2; k += 256) hist[k] = 0;
        __syncthreads();
        const int e0 = bid * HB_PER;
#pragma unroll 4
        for (int k = tid; k < HB_PER; k += 256)
            atomicAdd(&hist[er[e0 + k] >> 5], 1);
        __syncthreads();
        for (int k = tid; k < NB2; k += 256) ghist[bid * NB2 + k] = hist[k];
    } else if (bid < HB_BLOCKS + XB_BLOCKS) {
        // ---- x -> bf16 (16 elements / thread) ----
        size_t base = ((size_t)(bid - HB_BLOCKS) * 256 + tid) * 16;
        float4 a = *reinterpret_cast<const float4*>(x + base);
        float4 b = *reinterpret_cast<const float4*>(x + base + 4);
        float4 c = *reinterpret_cast<const float4*>(x + base + 8);
        float4 d = *reinterpret_cast<const float4*>(x + base + 12);
        uint4 o1, o2;
        o1.x = (uint)f2bf(a.x) | ((uint)f2bf(a.y) << 16);
        o1.y = (uint)f2bf(a.z) | ((uint)f2bf(a.w) << 16);
        o1.z = (uint)f2bf(b.x) | ((uint)f2bf(b.y) << 16);
        o1.w = (uint)f2bf(b.z) | ((uint)f2bf(b.w) << 16);
        o2.x = (uint)f2bf(c.x) | ((uint)f2bf(c.y) << 16);
        o2.y = (uint)f2bf(c.z) | ((uint)f2bf(c.w) << 16);
        o2.z = (uint)f2bf(d.x) | ((uint)f2bf(d.y) << 16);
        o2.w = (uint)f2bf(d.z) | ((uint)f2bf(d.w) << 16);
        *reinterpret_cast<uint4*>(xb + base) = o1;
        *reinterpret_cast<uint4*>(xb + base + 8) = o2;
    } else {
        // ---- pack weights ----
        int idx = (bid - HB_BLOCKS - XB_BLOCKS) * 256 + tid;   // 0 .. 81919
        if (idx < 65536) {
            int jj = idx & 7;
            int lane = (idx >> 3) & 63;
            int tile = idx >> 9;          // 0..127
            int nt = tile & 15, kt = tile >> 4;
            int k = kt * 32 + (lane >> 4) * 8 + jj;
            int j = nt * 16 + (lane & 15);
            float v;
            if (j < 128) v = (k < 128) ? Wg1[j * 128 + k] : Wg2[j * 128 + (k - 128)];
            else { int c = j - 128; v = (k < 128) ? Wb1[c * 128 + k] : Wb2[c * 128 + (k - 128)]; }
            W1p[idx] = f2bf(v);
        } else if (idx < 81920) {
            int i2 = idx - 65536;
            int jj = i2 & 7;
            int lane = (i2 >> 3) & 63;
            int tile = i2 >> 9;           // 0..31
            int nt = tile & 7, kt = tile >> 3;
            int k = kt * 32 + (lane >> 4) * 8 + jj;
            int j = nt * 16 + (lane & 15);
            W2p[i2] = f2bf(gcw[k * 128 + j]);
        }
    }
}

// ---------------------------------------------------------------------------
// Single-kernel scan: block = 64 bins x 4 partials (R9 form).
// ---------------------------------------------------------------------------
__global__ __launch_bounds__(256) void scan_merge(
    const int* __restrict__ ghist, int* __restrict__ gbase,
    int* __restrict__ cursorB)
{
    __shared__ int S[4][64];
    const int tid = threadIdx.x;
    const int cl = tid & 63;              // local bin
    const int p = tid >> 6;               // partial 0..3 (64 chunks each)
    const int c = blockIdx.x * 64 + cl;
    const bool ok = c < NB2;

    int acc = 0;
    if (ok) {
#pragma unroll 8
        for (int r = p * 64; r < p * 64 + 64; r++) acc += ghist[r * NB2 + c];
    }
    S[p][cl] = acc;
    __syncthreads();

    if (ok) {
        int base = c * SCAP;
        for (int q = 0; q < p; q++) base += S[q][cl];
#pragma unroll 8
        for (int r = p * 64; r < p * 64 + 64; r++) {
            gbase[r * NB2 + c] = base;
            base += ghist[r * NB2 + c];
        }
        if (p == 3) cursorB[c] = base - c * SCAP;
    }
}

// ---------------------------------------------------------------------------
// Replay scatter (R9 form — fully cached; R10 measured nt store here +50us,
// R11 measured nt loads in prep −27us total): LDS slot claim, direct store.
// staging entry: {(col<<13) | rowlocal(5b), val_bits}
// ---------------------------------------------------------------------------
__global__ __launch_bounds__(512) void scatter_edges(
    const int* __restrict__ er, const int* __restrict__ ec,
    const float* __restrict__ ev, const int* __restrict__ gbase,
    int2* __restrict__ stg)
{
    __shared__ int cur[NB2];                       // 12.5KB
    const int bid = blockIdx.x;
    const int tid = threadIdx.x;
    for (int k = tid; k < NB2; k += 512) cur[k] = gbase[bid * NB2 + k];
    __syncthreads();
    const int e0 = bid * HB_PER;
#pragma unroll 4
    for (int k = tid; k < HB_PER; k += 512) {
        int e = e0 + k;
        int r = er[e];
        int t = atomicAdd(&cur[r >> 5], 1);        // LDS slot claim
        int2 o;
        o.x = (ec[e] << 13) | (r & 31);
        o.y = __float_as_int(ev[e]);
        stg[t] = o;                                // cached scattered store
    }
}

// ---------------------------------------------------------------------------
// Fully fused (R11 form — its nt hints are A/B-verified: 99.5 -> 95.5us,
// FETCH 193 -> 189MB), 8 waves/block (512 thr), EXACTLY 32KB LDS.
//   LDS map:
//     [0,     16384) asb : As[32][512B row: x(256)|nb(256)], swizzled
//     [16384, 24576) elist: 1024 int2 (sort output)
//     [24576, 25092) sort scratch (dead after gather)
//     [16384, 32768) gbb : GB[32][512B] bf16 — written only AFTER gather
//   nt policy: bucket loads (read-once) and hk/mout stores (write-once,
//   coalesced) are NONTEMPORAL so xb gather rows keep the L2.
//   gather  : work-stealing rows; 4x16-lane groups; edges from LDS; unroll 2.
//   phase 1 : [G|B](32x256) = As @ W1p -> GB (LDS, bf16)
//   phase1.5: gamma/beta/m/t elementwise
//   phase 2 : h_k = (t @ W2p) / (norm+1)
// NOTE: stg aliases hk (bucket b == hk rows of block b); reads complete into
// registers before any hk store, separated by __syncthreads -> no race.
// ---------------------------------------------------------------------------
__global__ __launch_bounds__(512, 8) void fused_all(
    const int* __restrict__ cursorB, const int2* stg,
    const ushort* __restrict__ xb,
    const float* __restrict__ norm, const float* __restrict__ rvec,
    const ushort* __restrict__ W1p, const ushort* __restrict__ W2p,
    float* hk, float* __restrict__ mout)
{
    __shared__ ushort SM[16384];          // 32768 B — the ONLY LDS object
    char* smb = (char*)SM;
    char* asb = smb;                      // [0, 16384)
    int2* elist = (int2*)(smb + 16384);   // [16384, 24576): 1024 entries
    int*  h32   = (int*)(smb + 24576);
    int*  rs32  = (int*)(smb + 24704);
    int*  pd32  = (int*)(smb + 24832);
    int*  cur32 = (int*)(smb + 24960);
    int*  rowctr= (int*)(smb + 25088);
    char* gbb = smb + 16384;              // GB region (post-gather only)

    const int tid = threadIdx.x;
    const int lane = tid & 63;
    const int w = tid >> 6;               // wave 0..7
    const int g = lane >> 4;              // edge slot 0..3
    const int s = lane & 15;              // 16B chunk within row
    const int b = blockIdx.x;
    const int node0 = b * BM;             // 3125 * 32 = 100000 exact

    // ---- bucket loads (conditional, nontemporal, issued before x-stage) ----
    const int cntE = cursorB[b];
    const int2* sb = stg + (size_t)b * SCAP;
    long long raw0 = 0, raw1 = 0;
    const bool v0 = tid < cntE, v1 = tid + 512 < cntE;   // cnt ~512, max ~650
    if (v0) raw0 = __builtin_nontemporal_load((const long long*)(sb + tid));
    if (v1) raw1 = __builtin_nontemporal_load((const long long*)(sb + tid + 512));
    int2 E0, E1;
    E0.x = (int)raw0; E0.y = (int)(raw0 >> 32);
    E1.x = (int)raw1; E1.y = (int)(raw1 >> 32);

    // ---- stage x-half of As (32 rows x 16 chunks of 16B), swizzled ----
    {
        int rr = tid >> 4;                       // row 0..31
        int cq = tid & 15;                       // 16B chunk
        uint4 v = *reinterpret_cast<const uint4*>(xb + (size_t)(node0 + rr) * 128 + cq * 8);
        *(uint4*)(asb + ((rr * 512 + cq * 16) ^ ((rr & 7) << 4))) = v;
    }

    // ---- 32-bin counting sort (padded to x8) ----
    if (tid < 32) h32[tid] = 0;
    if (tid == 32) *rowctr = 0;
    __syncthreads();
    if (v0) atomicAdd(&h32[E0.x & 31], 1);
    if (v1) atomicAdd(&h32[E1.x & 31], 1);
    __syncthreads();
    if (tid < 64) {
        int pc = 0;
        if (tid < 32) { int h = h32[tid]; pc = (h + 7) & ~7; cur32[tid] = 0; }
        int v = pc;
        for (int off = 1; off < 32; off <<= 1) {
            int t = __shfl_up(v, off, 64);
            if (lane >= off) v += t;
        }
        if (tid < 32) { rs32[tid] = v - pc; pd32[tid] = pc; }
    }
    __syncthreads();
    if (v0) { int rl = E0.x & 31; elist[rs32[rl] + atomicAdd(&cur32[rl], 1)] = E0; }
    if (v1) { int rl = E1.x & 31; elist[rs32[rl] + atomicAdd(&cur32[rl], 1)] = E1; }
    if (tid < 32) {                        // pad tail with {col=0, val=0}
        int rs = rs32[tid];
        for (int j = h32[tid]; j < pd32[tid]; ++j) elist[rs + j] = make_int2(tid, 0);
    }
    __syncthreads();

    // ---- gather nb rows (SpMM): work-stealing rows, edges from LDS ----
    const char* xbase = (const char*)xb + s * 16;
    for (;;) {
        int rr;
        if (lane == 0) rr = atomicAdd(rowctr, 1);
        rr = __shfl(rr, 0, 64);
        if (rr >= 32) break;
        const int2* el = elist + rs32[rr];
        int pd = pd32[rr];
        float ac0 = 0.f, ac1 = 0.f, ac2 = 0.f, ac3 = 0.f;
        float ac4 = 0.f, ac5 = 0.f, ac6 = 0.f, ac7 = 0.f;
#pragma unroll 2
        for (int j = 0; j < pd; j += 8) {
            int2 e0 = el[j + g];
            int2 e1 = el[j + 4 + g];
            uint4 q0 = *reinterpret_cast<const uint4*>(xbase + (e0.x >> 5));  // >>5 = col*256
            uint4 q1 = *reinterpret_cast<const uint4*>(xbase + (e1.x >> 5));
            float f0 = __int_as_float(e0.y);
            float f1 = __int_as_float(e1.y);
            ac0 += f0 * blo(q0.x); ac1 += f0 * bhi(q0.x);
            ac2 += f0 * blo(q0.y); ac3 += f0 * bhi(q0.y);
            ac4 += f0 * blo(q0.z); ac5 += f0 * bhi(q0.z);
            ac6 += f0 * blo(q0.w); ac7 += f0 * bhi(q0.w);
            ac0 += f1 * blo(q1.x); ac1 += f1 * bhi(q1.x);
            ac2 += f1 * blo(q1.y); ac3 += f1 * bhi(q1.y);
            ac4 += f1 * blo(q1.z); ac5 += f1 * bhi(q1.z);
            ac6 += f1 * blo(q1.w); ac7 += f1 * bhi(q1.w);
        }
        ac0 += __shfl_xor(ac0, 16, 64); ac0 += __shfl_xor(ac0, 32, 64);
        ac1 += __shfl_xor(ac1, 16, 64); ac1 += __shfl_xor(ac1, 32, 64);
        ac2 += __shfl_xor(ac2, 16, 64); ac2 += __shfl_xor(ac2, 32, 64);
        ac3 += __shfl_xor(ac3, 16, 64); ac3 += __shfl_xor(ac3, 32, 64);
        ac4 += __shfl_xor(ac4, 16, 64); ac4 += __shfl_xor(ac4, 32, 64);
        ac5 += __shfl_xor(ac5, 16, 64); ac5 += __shfl_xor(ac5, 32, 64);
        ac6 += __shfl_xor(ac6, 16, 64); ac6 += __shfl_xor(ac6, 32, 64);
        ac7 += __shfl_xor(ac7, 16, 64); ac7 += __shfl_xor(ac7, 32, 64);
        if (g == 0) {
            uint4 o;
            o.x = (uint)f2bf(ac0) | ((uint)f2bf(ac1) << 16);
            o.y = (uint)f2bf(ac2) | ((uint)f2bf(ac3) << 16);
            o.z = (uint)f2bf(ac4) | ((uint)f2bf(ac5) << 16);
            o.w = (uint)f2bf(ac6) | ((uint)f2bf(ac7) << 16);
            *(uint4*)(asb + ((rr * 512 + 256 + s * 16) ^ ((rr & 7) << 4))) = o;
        }
    }
    __syncthreads();

    // ---- phase 1: [G|B] = As @ W1  (each wave: 2 N-tiles) ----
    f32x4 acc[2][2];
#pragma unroll
    for (int mt = 0; mt < 2; mt++)
#pragma unroll
        for (int nl = 0; nl < 2; nl++) acc[mt][nl] = (f32x4){0.f, 0.f, 0.f, 0.f};

#pragma unroll
    for (int kt = 0; kt < 8; kt++) {
        bf16x8 af[2];
#pragma unroll
        for (int mt = 0; mt < 2; mt++) {
            int row = mt * 16 + (lane & 15);
            int off = (row * 512 + kt * 64 + (lane >> 4) * 16) ^ ((row & 7) << 4);
            af[mt] = *(bf16x8*)(asb + off);
        }
#pragma unroll
        for (int nl = 0; nl < 2; nl++) {
            int nt = w * 2 + nl;
            bf16x8 bfg = *(const bf16x8*)(W1p + (((kt * 16 + nt) * 64 + lane) << 3));
#pragma unroll
            for (int mt = 0; mt < 2; mt++)
                acc[mt][nl] = __builtin_amdgcn_mfma_f32_16x16x32_bf16(af[mt], bfg, acc[mt][nl], 0, 0, 0);
        }
    }

    // ---- write GB to LDS as bf16 (elist/scratch dead past this barrier) ----
#pragma unroll
    for (int mt = 0; mt < 2; mt++)
#pragma unroll
        for (int nl = 0; nl < 2; nl++) {
            int j = (w * 2 + nl) * 16 + (lane & 15);
#pragma unroll
            for (int reg = 0; reg < 4; reg++) {
                int row = mt * 16 + (lane >> 4) * 4 + reg;
                int off = (row * 512 + j * 2) ^ ((row & 7) << 4);
                *(ushort*)(gbb + off) = f2bf(acc[mt][nl][reg]);
            }
        }
    __syncthreads();

    // ---- phase 1.5: elementwise; write m (nontemporal); t -> As in place ----
    {
        int c = tid & 127;
        float rv = rvec[c];
        int rg = tid >> 7;                // 0..3
#pragma unroll 4
        for (int i = 0; i < 8; i++) {
            int row = rg * 8 + i;
            int swz = (row & 7) << 4;
            int bx = (row * 512 + c * 2) ^ swz;
            int bn = (row * 512 + 256 + c * 2) ^ swz;
            float graw = bf2f(*(ushort*)(gbb + bx));
            float braw = bf2f(*(ushort*)(gbb + bn));
            float xv = bf2f(*(ushort*)(asb + bx));
            float nv = bf2f(*(ushort*)(asb + bn));
            float gamma = ((graw > 0.f) ? graw : LRELU_SLOPE * graw) + 1.f;
            float beta = (braw > 0.f) ? braw : LRELU_SLOPE * braw;
            float gb_ = gamma * rv + beta;
            float mv = xv + gb_ - nv;
            float tv = 2.f * xv + gb_;
            __builtin_nontemporal_store(mv, &mout[(size_t)(node0 + row) * 128 + c]);
            *(ushort*)(asb + bx) = f2bf(tv);
        }
    }
    __syncthreads();

    // ---- phase 2: h_k = t @ W2 / (norm+1)  (each wave: 1 N-tile) ----
    f32x4 acc2[2];
#pragma unroll
    for (int mt = 0; mt < 2; mt++) acc2[mt] = (f32x4){0.f, 0.f, 0.f, 0.f};

#pragma unroll
    for (int kt = 0; kt < 4; kt++) {
        bf16x8 af[2];
#pragma unroll
        for (int mt = 0; mt < 2; mt++) {
            int row = mt * 16 + (lane & 15);
            int off = (row * 512 + kt * 64 + (lane >> 4) * 16) ^ ((row & 7) << 4);
            af[mt] = *(bf16x8*)(asb + off);
        }
        bf16x8 bfg = *(const bf16x8*)(W2p + (((kt * 8 + w) * 64 + lane) << 3));
#pragma unroll
        for (int mt = 0; mt < 2; mt++)
            acc2[mt] = __builtin_amdgcn_mfma_f32_16x16x32_bf16(af[mt], bfg, acc2[mt], 0, 0, 0);
    }

#pragma unroll
    for (int mt = 0; mt < 2; mt++) {
        int col = w * 16 + (lane & 15);
#pragma unroll
        for (int reg = 0; reg < 4; reg++) {
            int row = mt * 16 + (lane >> 4) * 4 + reg;
            int node = node0 + row;
            float inv = 1.f / (norm[node] + 1.f);
            __builtin_nontemporal_store(acc2[mt][reg] * inv,
                                        &hk[(size_t)node * 128 + col]);
        }
    }
}

extern "C" void kernel_launch(void* const* d_in, const int* in_sizes, int n_in,
                              void* d_out, int out_size, void* d_ws, size_t ws_size,
                              hipStream_t stream)
{
    const float* x    = (const float*)d_in[0];
    const int*   er   = (const int*)d_in[1];
    const int*   ec   = (const int*)d_in[2];
    const float* ev   = (const float*)d_in[3];
    const float* norm = (const float*)d_in[4];
    const float* Wg1  = (const float*)d_in[5];
    const float* Wg2  = (const float*)d_in[6];
    const float* Wb1  = (const float*)d_in[7];
    const float* Wb2  = (const float*)d_in[8];
    const float* r    = (const float*)d_in[9];
    const float* gcw  = (const float*)d_in[10];

    float* out  = (float*)d_out;
    float* hk   = out;
    float* mout = out + (size_t)N_NODES * NFEAT;

    // workspace layout (~32MB total)
    ushort* xb      = (ushort*)d_ws;                         // N*128 bf16 = 25.6MB
    ushort* W1p     = xb + (size_t)N_NODES * NFEAT;          // 65536
    ushort* W2p     = W1p + 65536;                           // 16384
    int*    cursorB = (int*)(W2p + 16384);                   // NB2
    int*    ghist   = cursorB + NB2;                         // 256*3125 = 3.2MB
    int*    gbase   = ghist + HB_BLOCKS * NB2;               // 3.2MB

    // bucket staging aliases hk: bucket b == hk rows of fused block b
    int2* stg = (int2*)hk;                                   // NB2*SCAP*8 = 51.2MB

    mega_prep<<<HB_BLOCKS + XB_BLOCKS + PK_BLOCKS, 256, 0, stream>>>(
        er, ghist, x, xb, Wg1, Wg2, Wb1, Wb2, gcw, W1p, W2p);

    scan_merge<<<(NB2 + 63) / 64, 256, 0, stream>>>(ghist, gbase, cursorB);

    scatter_edges<<<HB_BLOCKS, 512, 0, stream>>>(er, ec, ev, gbase, stg);

    fused_all<<<NB2, 512, 0, stream>>>(
        cursorB, stg, xb, norm, r, W1p, W2p, hk, mout);
}